// Round 4
// baseline (152.498 us; speedup 1.0000x reference)
//
#include <hip/hip_runtime.h>
#include <stdint.h>

#define NUM_EMBED 1024
#define EMBED_DIM 256
#define HW        1024
#define OUT_ELEMS 8388608
#define NBLK      256
#define MAGIC_E   0x5F3759DF
#define MAGIC_D   0x2545F491

typedef float f32x4 __attribute__((ext_vector_type(4)));

// async global->LDS, 16B per lane (wave-uniform base + lane*16)
static __device__ __forceinline__ void gl_lds16(const void* g, void* l) {
    __builtin_amdgcn_global_load_lds(
        (const __attribute__((address_space(1))) void*)g,
        (__attribute__((address_space(3))) void*)l, 16, 0, 0);
}

// pack 4 floats -> 4 fp8 e4m3 (one dword), RNE
static __device__ __forceinline__ uint32_t pk4_fp8(float a, float b, float c, float d) {
    int r = __builtin_amdgcn_cvt_pk_fp8_f32(a, b, 0, false);
    r = __builtin_amdgcn_cvt_pk_fp8_f32(c, d, r, true);
    return (uint32_t)r;
}

// ---------------------------------------------------------------------------
// Fully fused VQ kernel. Grid = 256 blocks x 256 threads, 1 block/CU
// (LDS ~103KB), so all blocks are co-resident -> the flag gates are safe.
//
// fp8 fragment layouts (8B slot per lane, k = kk*32 + quad*8 + j):
//   E (global ef8): slot8B = (k16*8 + kk)*64 + quad*16 + l16, code=k16*16+l16
//   X (LDS Xs, swizzled): byte = row*256 + ((kk*4+quad) ^ (row&31))*8
// E pre-scaled x1024 (values ~U(-1,1)); dist = ||e||^2 - 2*dot/1024.
// ---------------------------------------------------------------------------
__global__ __launch_bounds__(256) void k_vq(
        const float* __restrict__ x, const float* __restrict__ cb,
        float* __restrict__ out, uint8_t* __restrict__ ef8,
        float* __restrict__ enorm, int* __restrict__ eflags,
        int* __restrict__ dflags, float* __restrict__ psum,
        float* __restrict__ loss_out) {
    __shared__ uint8_t Es[2][32768];   // E double buffer (128 codes x 256 k)
    __shared__ uint8_t Xs[32768];      // X tile, swizzled fp8
    __shared__ float   en_s[NUM_EMBED];
    __shared__ float   red[128][2];
    __shared__ float   wpart[8];       // [0..3]=x2 wave sums, [4..7]=dmin wave sums
    __shared__ double  wsd[4];

    const int t = threadIdx.x, bid = blockIdx.x;
    const int w = t >> 6, lane = t & 63, l16 = lane & 15, quad = lane >> 4;

    // ---- codebook mini-prep: this block's 4 codes (wave w -> one code) ----
    {
        int k = bid * 4 + w;
        float4 v = reinterpret_cast<const float4*>(cb)[k * 64 + lane];
        float ss = v.x * v.x + v.y * v.y + v.z * v.z + v.w * v.w;
        uint32_t p = pk4_fp8(v.x * 1024.f, v.y * 1024.f, v.z * 1024.f, v.w * 1024.f);
        int k16 = k >> 4, kr = k & 15;
        int kk = lane >> 3, qd = (lane >> 1) & 3, hf = lane & 1;
        reinterpret_cast<uint32_t*>(ef8)[
            (((k16 * 8 + kk) * 64 + qd * 16 + kr) << 1) + hf] = p;
        #pragma unroll
        for (int off = 1; off < 64; off <<= 1) ss += __shfl_xor(ss, off);
        if (lane == 0) enorm[k] = ss;
    }
    __threadfence();
    __syncthreads();
    if (t == 0)
        __hip_atomic_store(&eflags[bid], MAGIC_E, __ATOMIC_RELEASE,
                           __HIP_MEMORY_SCOPE_AGENT);

    // ---- gate: wait until all 256 codebook pieces are published ----
    if (t < 64) {
        while (__hip_atomic_load(&eflags[t],       __ATOMIC_ACQUIRE, __HIP_MEMORY_SCOPE_AGENT) != MAGIC_E ||
               __hip_atomic_load(&eflags[t + 64],  __ATOMIC_ACQUIRE, __HIP_MEMORY_SCOPE_AGENT) != MAGIC_E ||
               __hip_atomic_load(&eflags[t + 128], __ATOMIC_ACQUIRE, __HIP_MEMORY_SCOPE_AGENT) != MAGIC_E ||
               __hip_atomic_load(&eflags[t + 192], __ATOMIC_ACQUIRE, __HIP_MEMORY_SCOPE_AGENT) != MAGIC_E)
            __builtin_amdgcn_s_sleep(2);
    }
    __syncthreads();

    // ---- prefetch E chunk 0 now; DMA overlaps all of phase X ----
    #pragma unroll
    for (int i = 0; i < 8; ++i) {
        int off = (i * 256 + t) * 16;
        gl_lds16((const char*)ef8 + off, (char*)&Es[0][0] + off);
    }
    #pragma unroll
    for (int i = 0; i < 4; ++i) en_s[t + i * 256] = enorm[t + i * 256];

    // ---- phase X: copy x->out, sum x^2, fp8-transpose into Xs ----
    const int b = bid >> 3;
    const int hw04 = (bid & 7) * 32;        // float4 index of hw0
    const int cg = t >> 5, hwq = t & 31;
    const float4* x4 = reinterpret_cast<const float4*>(x);
    float4* o4 = reinterpret_cast<float4*>(out);
    float sx2 = 0.f;
    #pragma unroll
    for (int j = 0; j < 4; ++j) {
        int c0 = cg * 32 + j * 8;
        size_t base = ((size_t)b * 256 + c0) * 256 + hw04 + hwq;
        float4 v[8];
        #pragma unroll
        for (int i = 0; i < 8; ++i) v[i] = x4[base + (size_t)i * 256];
        #pragma unroll
        for (int i = 0; i < 8; ++i) o4[base + (size_t)i * 256] = v[i];
        #pragma unroll
        for (int i = 0; i < 8; ++i)
            sx2 += v[i].x * v[i].x + v[i].y * v[i].y
                 + v[i].z * v[i].z + v[i].w * v[i].w;
        int g = cg * 4 + j;
        const float* f = reinterpret_cast<const float*>(v);
        #pragma unroll
        for (int r = 0; r < 4; ++r) {
            int row = 4 * hwq + r;
            uint2 pc;
            pc.x = pk4_fp8(f[0 * 4 + r], f[1 * 4 + r], f[2 * 4 + r], f[3 * 4 + r]);
            pc.y = pk4_fp8(f[4 * 4 + r], f[5 * 4 + r], f[6 * 4 + r], f[7 * 4 + r]);
            *reinterpret_cast<uint2*>(
                &Xs[row * 256 + ((g ^ (row & 31)) << 3)]) = pc;
        }
    }
    #pragma unroll
    for (int off = 1; off < 64; off <<= 1) sx2 += __shfl_xor(sx2, off);
    if (lane == 0) wpart[w] = sx2;

    __syncthreads();   // Xs complete, chunk-0 DMA drained, en_s ready

    // ---- gather A fragments (64 rows x 256 k per wave) into registers ----
    const int rg = w >> 1, h = w & 1;
    long a[4][8];
    #pragma unroll
    for (int rt = 0; rt < 4; ++rt) {
        int row = rg * 64 + rt * 16 + l16;
        int r31 = row & 31;
        #pragma unroll
        for (int kk = 0; kk < 8; ++kk) {
            int g = kk * 4 + quad;
            a[rt][kk] = *reinterpret_cast<const long*>(
                &Xs[row * 256 + ((g ^ r31) << 3)]);
        }
    }

    float dmin[4][4];
    #pragma unroll
    for (int rt = 0; rt < 4; ++rt)
        #pragma unroll
        for (int r = 0; r < 4; ++r) dmin[rt][r] = 1e30f;

    // ---- E-stream loop: 8 chunks of 128 codes, double-buffered ----
    for (int s = 0; s < 8; ++s) {
        if (s + 1 < 8) {
            const char* src = (const char*)ef8 + (size_t)(s + 1) * 32768;
            char* ldst = (char*)&Es[(s + 1) & 1][0];
            #pragma unroll
            for (int i = 0; i < 8; ++i) {
                int off = (i * 256 + t) * 16;
                gl_lds16(src + off, ldst + off);
            }
        }

        const uint8_t* buf = &Es[s & 1][0];
        f32x4 acc[4][4];
        #pragma unroll
        for (int rt = 0; rt < 4; ++rt)
            #pragma unroll
            for (int ct = 0; ct < 4; ++ct) {
                f32x4 z = {0.f, 0.f, 0.f, 0.f};
                acc[rt][ct] = z;
            }

        #pragma unroll
        for (int kk = 0; kk < 8; ++kk) {
            long bfr[4];
            #pragma unroll
            for (int ct = 0; ct < 4; ++ct)
                bfr[ct] = *reinterpret_cast<const long*>(
                    buf + ((((h * 4 + ct) * 8 + kk) * 64 + lane) << 3));
            #pragma unroll
            for (int rt = 0; rt < 4; ++rt)
                #pragma unroll
                for (int ct = 0; ct < 4; ++ct)
                    acc[rt][ct] = __builtin_amdgcn_mfma_f32_16x16x32_fp8_fp8(
                        a[rt][kk], bfr[ct], acc[rt][ct], 0, 0, 0);
        }

        #pragma unroll
        for (int ct = 0; ct < 4; ++ct) {
            float en = en_s[s * 128 + h * 64 + ct * 16 + l16];
            #pragma unroll
            for (int rt = 0; rt < 4; ++rt)
                #pragma unroll
                for (int r = 0; r < 4; ++r)
                    dmin[rt][r] = fminf(dmin[rt][r],
                                        fmaf(acc[rt][ct][r], -0.001953125f, en));
        }
        __syncthreads();
    }

    // ---- min over the 16 code-columns sharing each row ----
    #pragma unroll
    for (int rt = 0; rt < 4; ++rt)
        #pragma unroll
        for (int r = 0; r < 4; ++r) {
            float v = dmin[rt][r];
            v = fminf(v, __shfl_xor(v, 1));
            v = fminf(v, __shfl_xor(v, 2));
            v = fminf(v, __shfl_xor(v, 4));
            v = fminf(v, __shfl_xor(v, 8));
            dmin[rt][r] = v;
        }
    if (l16 == 0) {
        #pragma unroll
        for (int rt = 0; rt < 4; ++rt)
            #pragma unroll
            for (int r = 0; r < 4; ++r)
                red[rg * 64 + rt * 16 + quad * 4 + r][h] = dmin[rt][r];
    }
    __syncthreads();

    // ---- block partial: sum of 128 row-mins + sum x^2 ----
    float sblk = 0.f;
    if (t < 128) sblk = fminf(red[t][0], red[t][1]);
    #pragma unroll
    for (int off = 1; off < 64; off <<= 1) sblk += __shfl_xor(sblk, off);
    if (lane == 0) wpart[4 + w] = sblk;
    __syncthreads();
    if (t == 0) {
        psum[bid] = wpart[0] + wpart[1] + wpart[2] + wpart[3]
                  + wpart[4] + wpart[5] + wpart[6] + wpart[7];
        __threadfence();
        __hip_atomic_store(&dflags[bid], MAGIC_D, __ATOMIC_RELEASE,
                           __HIP_MEMORY_SCOPE_AGENT);
    }

    // ---- finisher block: wait for all partials, write loss ----
    if (bid == NBLK - 1) {
        if (t < 64) {
            while (__hip_atomic_load(&dflags[t],       __ATOMIC_ACQUIRE, __HIP_MEMORY_SCOPE_AGENT) != MAGIC_D ||
                   __hip_atomic_load(&dflags[t + 64],  __ATOMIC_ACQUIRE, __HIP_MEMORY_SCOPE_AGENT) != MAGIC_D ||
                   __hip_atomic_load(&dflags[t + 128], __ATOMIC_ACQUIRE, __HIP_MEMORY_SCOPE_AGENT) != MAGIC_D ||
                   __hip_atomic_load(&dflags[t + 192], __ATOMIC_ACQUIRE, __HIP_MEMORY_SCOPE_AGENT) != MAGIC_D)
                __builtin_amdgcn_s_sleep(2);
        }
        __syncthreads();
        double sd = (double)((volatile const float*)psum)[t];
        #pragma unroll
        for (int off = 1; off < 64; off <<= 1) sd += __shfl_xor(sd, off);
        if (lane == 0) wsd[w] = sd;
        __syncthreads();
        if (t == 0)
            loss_out[0] = (float)(1.25 * (wsd[0] + wsd[1] + wsd[2] + wsd[3])
                                  / (double)OUT_ELEMS);
    }
}

extern "C" void kernel_launch(void* const* d_in, const int* in_sizes, int n_in,
                              void* d_out, int out_size, void* d_ws, size_t ws_size,
                              hipStream_t stream) {
    const float* x  = (const float*)d_in[0];   // [32,256,32,32] fp32
    const float* cb = (const float*)d_in[1];   // [1024,256] fp32
    float* out = (float*)d_out;                // 8388608 out + 1 loss

    char* ws = (char*)d_ws;
    int*     eflags = (int*)ws;                 // 1 KB
    int*     dflags = (int*)(ws + 1024);        // 1 KB
    float*   psum   = (float*)(ws + 2048);      // 1 KB
    float*   enorm  = (float*)(ws + 4096);      // 4 KB
    uint8_t* ef8    = (uint8_t*)(ws + 8192);    // 256 KB

    hipLaunchKernelGGL(k_vq, dim3(NBLK), dim3(256), 0, stream,
                       x, cb, out, ef8, enorm, eflags, dflags, psum,
                       out + OUT_ELEMS);
}

// Round 5
// 109.158 us; speedup vs baseline: 1.3970x; 1.3970x over previous
//
#include <hip/hip_runtime.h>
#include <stdint.h>

#define NUM_EMBED 1024
#define EMBED_DIM 256
#define HW        1024
#define OUT_ELEMS 8388608
#define NBLK2     512

typedef float f32x4 __attribute__((ext_vector_type(4)));

// async global->LDS, 16B per lane (wave-uniform base + lane*16)
static __device__ __forceinline__ void gl_lds16(const void* g, void* l) {
    __builtin_amdgcn_global_load_lds(
        (const __attribute__((address_space(1))) void*)g,
        (__attribute__((address_space(3))) void*)l, 16, 0, 0);
}

// pack 4 floats -> 4 fp8 e4m3 (one dword), RNE
static __device__ __forceinline__ uint32_t pk4_fp8(float a, float b, float c, float d) {
    int r = __builtin_amdgcn_cvt_pk_fp8_f32(a, b, 0, false);
    r = __builtin_amdgcn_cvt_pk_fp8_f32(c, d, r, true);
    return (uint32_t)r;
}

// ---------------------------------------------------------------------------
// fp8 E fragment layout in global ef8 (8B slot per lane, k = kk*32 + quad*8 + j):
//   slot8B = (k16*8 + kk)*64 + quad*16 + l16, code = k16*16 + l16
// E pre-scaled x1024 (values ~U(-1,1)); dist = ||e||^2 - 2*dot/1024.
// ---------------------------------------------------------------------------

// K1: codebook -> fp8 frags + enorm, ticket=0.  64 blocks x 256 (R3-proven).
__global__ __launch_bounds__(256) void k_codeprep(
        const float* __restrict__ cb, uint8_t* __restrict__ ef8,
        float* __restrict__ enorm, int* __restrict__ ticket) {
    int t = threadIdx.x;
    if (blockIdx.x == 0 && t == 0) *ticket = 0;
    int k16 = blockIdx.x;
    int kr = t >> 4;              // code within tile (= l16)
    int s  = t & 15;              // k-segment: k = s*16 .. +16
    int code = k16 * 16 + kr;

    const float4* src = reinterpret_cast<const float4*>(
        cb + (size_t)code * EMBED_DIM + s * 16);
    float4 v0 = src[0], v1 = src[1], v2 = src[2], v3 = src[3];
    float f[16] = {v0.x, v0.y, v0.z, v0.w, v1.x, v1.y, v1.z, v1.w,
                   v2.x, v2.y, v2.z, v2.w, v3.x, v3.y, v3.z, v3.w};

    float ss = 0.f;
    #pragma unroll
    for (int m = 0; m < 16; ++m) ss += f[m] * f[m];   // exact ||e||^2

    int kk = s >> 1;
    int q0 = (s & 1) * 2;
    uint2 pc0, pc1;
    pc0.x = pk4_fp8(f[0]*1024.f,  f[1]*1024.f,  f[2]*1024.f,  f[3]*1024.f);
    pc0.y = pk4_fp8(f[4]*1024.f,  f[5]*1024.f,  f[6]*1024.f,  f[7]*1024.f);
    pc1.x = pk4_fp8(f[8]*1024.f,  f[9]*1024.f,  f[10]*1024.f, f[11]*1024.f);
    pc1.y = pk4_fp8(f[12]*1024.f, f[13]*1024.f, f[14]*1024.f, f[15]*1024.f);
    uint2* dst = reinterpret_cast<uint2*>(ef8);
    dst[((size_t)k16 * 8 + kk) * 64 + (q0 + 0) * 16 + kr] = pc0;
    dst[((size_t)k16 * 8 + kk) * 64 + (q0 + 1) * 16 + kr] = pc1;

    #pragma unroll
    for (int off = 1; off < 16; off <<= 1) ss += __shfl_xor(ss, off);
    if (s == 0) enorm[code] = ss;
}

// ---------------------------------------------------------------------------
// K2: fused copy + fp8-transpose (LDS, reusing Es[1]) + MFMA min-dist.
// 512 blocks x 256 thr (4 waves), 64 rows/block, 2 blocks/CU (LDS ~71KB).
// Wave w handles ALL 64 rows x codes [w*32, w*32+32) of each 128-code chunk.
// X swizzle (granule=8B): byte = row*256 + ((g ^ (row&31))<<3), g = c>>3.
// ---------------------------------------------------------------------------
__global__ __launch_bounds__(256, 2) void k_main(
        const float* __restrict__ x, float* __restrict__ out,
        const uint8_t* __restrict__ ef8, const float* __restrict__ enorm,
        float* __restrict__ psum, int* __restrict__ ticket,
        float* __restrict__ loss_out) {
    __shared__ uint8_t Es[2][32768];   // [1] doubles as X-transpose scratch
    __shared__ float  en_s[NUM_EMBED];
    __shared__ float  red[64][4];
    __shared__ float  wpart[4];
    __shared__ double wsd[4];
    __shared__ int    last;

    const int t = threadIdx.x, bid = blockIdx.x;
    const int w = t >> 6, lane = t & 63, l16 = lane & 15, quad = lane >> 4;

    // ---- prefetch E chunk 0 (overlaps all of phase X) ----
    #pragma unroll
    for (int i = 0; i < 8; ++i) {
        int off = (i * 256 + t) * 16;
        gl_lds16((const char*)ef8 + off, (char*)&Es[0][0] + off);
    }

    // ---- phase X: copy x->out, sum x^2, fp8-transpose into Es[1] ----
    // block = batch b, hw slice of 64: rows local 0..63.
    const int b    = bid >> 4;
    const int hw04 = (bid & 15) * 16;      // float4 index of hw0 (16 f4 = 64 floats)
    const int hwq  = t & 15;               // f4 within slice
    const int cset = t >> 4;               // 16 channels per cset
    const float4* x4 = reinterpret_cast<const float4*>(x);
    float4* o4 = reinterpret_cast<float4*>(out);
    uint8_t* Xs = &Es[1][0];
    float sx2 = 0.f;
    #pragma unroll
    for (int j = 0; j < 2; ++j) {
        size_t base = ((size_t)b * 256 + cset * 16 + j * 8) * 256 + hw04 + hwq;
        float4 v[8];
        #pragma unroll
        for (int i = 0; i < 8; ++i) v[i] = x4[base + (size_t)i * 256];
        #pragma unroll
        for (int i = 0; i < 8; ++i) o4[base + (size_t)i * 256] = v[i];
        #pragma unroll
        for (int i = 0; i < 8; ++i)
            sx2 += v[i].x * v[i].x + v[i].y * v[i].y
                 + v[i].z * v[i].z + v[i].w * v[i].w;
        const float* f = reinterpret_cast<const float*>(v);
        int g = cset * 2 + j;              // channel granule (8 channels)
        #pragma unroll
        for (int r = 0; r < 4; ++r) {
            int row = hwq * 4 + r;         // local row 0..63
            uint2 pc;
            pc.x = pk4_fp8(f[0 * 4 + r], f[1 * 4 + r], f[2 * 4 + r], f[3 * 4 + r]);
            pc.y = pk4_fp8(f[4 * 4 + r], f[5 * 4 + r], f[6 * 4 + r], f[7 * 4 + r]);
            *reinterpret_cast<uint2*>(&Xs[row * 256 + ((g ^ (row & 31)) << 3)]) = pc;
        }
    }
    #pragma unroll
    for (int off = 1; off < 64; off <<= 1) sx2 += __shfl_xor(sx2, off);
    if (lane == 0) wpart[w] = sx2;

    #pragma unroll
    for (int i = 0; i < 4; ++i) en_s[t + i * 256] = enorm[t + i * 256];

    __syncthreads();   // Xs complete, chunk-0 DMA drained, en_s ready

    // ---- gather A fragments (all 64 rows x 256 k) into registers ----
    long a[4][8];
    #pragma unroll
    for (int rt = 0; rt < 4; ++rt) {
        int row = rt * 16 + l16;
        int r31 = row & 31;
        #pragma unroll
        for (int kk = 0; kk < 8; ++kk) {
            int g = kk * 4 + quad;
            a[rt][kk] = *reinterpret_cast<const long*>(
                &Xs[row * 256 + ((g ^ r31) << 3)]);
        }
    }
    __syncthreads();   // gathers done before chunk-1 prefetch overwrites Es[1]

    float dmin[4][4];
    #pragma unroll
    for (int rt = 0; rt < 4; ++rt)
        #pragma unroll
        for (int r = 0; r < 4; ++r) dmin[rt][r] = 1e30f;

    // ---- E-stream loop: 8 chunks of 128 codes, double-buffered ----
    for (int s = 0; s < 8; ++s) {
        if (s + 1 < 8) {
            const char* src = (const char*)ef8 + (size_t)(s + 1) * 32768;
            char* ldst = (char*)&Es[(s + 1) & 1][0];
            #pragma unroll
            for (int i = 0; i < 8; ++i) {
                int off = (i * 256 + t) * 16;
                gl_lds16(src + off, ldst + off);
            }
        }

        const uint8_t* buf = &Es[s & 1][0];
        f32x4 acc[4][2];
        #pragma unroll
        for (int rt = 0; rt < 4; ++rt)
            #pragma unroll
            for (int ct = 0; ct < 2; ++ct) {
                f32x4 z = {0.f, 0.f, 0.f, 0.f};
                acc[rt][ct] = z;
            }

        #pragma unroll
        for (int kk = 0; kk < 8; ++kk) {
            long bfr[2];
            #pragma unroll
            for (int ct = 0; ct < 2; ++ct)
                bfr[ct] = *reinterpret_cast<const long*>(
                    buf + ((((w * 2 + ct) * 8 + kk) * 64 + lane) << 3));
            #pragma unroll
            for (int rt = 0; rt < 4; ++rt)
                #pragma unroll
                for (int ct = 0; ct < 2; ++ct)
                    acc[rt][ct] = __builtin_amdgcn_mfma_f32_16x16x32_fp8_fp8(
                        a[rt][kk], bfr[ct], acc[rt][ct], 0, 0, 0);
        }

        #pragma unroll
        for (int ct = 0; ct < 2; ++ct) {
            float en = en_s[s * 128 + w * 32 + ct * 16 + l16];
            #pragma unroll
            for (int rt = 0; rt < 4; ++rt)
                #pragma unroll
                for (int r = 0; r < 4; ++r)
                    dmin[rt][r] = fminf(dmin[rt][r],
                                        fmaf(acc[rt][ct][r], -0.001953125f, en));
        }
        __syncthreads();
    }

    // ---- min over the 16 code-columns sharing each row ----
    #pragma unroll
    for (int rt = 0; rt < 4; ++rt)
        #pragma unroll
        for (int r = 0; r < 4; ++r) {
            float v = dmin[rt][r];
            v = fminf(v, __shfl_xor(v, 1));
            v = fminf(v, __shfl_xor(v, 2));
            v = fminf(v, __shfl_xor(v, 4));
            v = fminf(v, __shfl_xor(v, 8));
            dmin[rt][r] = v;
        }
    if (l16 == 0) {
        #pragma unroll
        for (int rt = 0; rt < 4; ++rt)
            #pragma unroll
            for (int r = 0; r < 4; ++r)
                red[rt * 16 + quad * 4 + r][w] = dmin[rt][r];
    }
    __syncthreads();

    // ---- block partial: sum of 64 row-mins (across 4 wave code-ranges) ----
    if (t < 64) {
        float m = fminf(fminf(red[t][0], red[t][1]),
                        fminf(red[t][2], red[t][3]));
        #pragma unroll
        for (int off = 1; off < 64; off <<= 1) m += __shfl_xor(m, off);
        if (t == 0) {
            psum[bid] = m + wpart[0] + wpart[1] + wpart[2] + wpart[3];
            __threadfence();
            int old = atomicAdd(ticket, 1);
            if (old == NBLK2 - 1) { __threadfence(); last = 1; }
            else last = 0;
        }
    }
    __syncthreads();

    if (last) {   // last-finishing block: final reduction + loss write
        const volatile float* vp = psum;
        double sd = (double)vp[t] + (double)vp[t + 256];
        #pragma unroll
        for (int off = 1; off < 64; off <<= 1) sd += __shfl_xor(sd, off);
        if (lane == 0) wsd[w] = sd;
        __syncthreads();
        if (t == 0)
            loss_out[0] = (float)(1.25 * (wsd[0] + wsd[1] + wsd[2] + wsd[3])
                                  / (double)OUT_ELEMS);
    }
}

extern "C" void kernel_launch(void* const* d_in, const int* in_sizes, int n_in,
                              void* d_out, int out_size, void* d_ws, size_t ws_size,
                              hipStream_t stream) {
    const float* x  = (const float*)d_in[0];   // [32,256,32,32] fp32
    const float* cb = (const float*)d_in[1];   // [1024,256] fp32
    float* out = (float*)d_out;                // 8388608 out + 1 loss

    char* ws = (char*)d_ws;
    int*     ticket = (int*)ws;                 // 4 B
    float*   psum   = (float*)(ws + 1024);      // 2 KB (512)
    float*   enorm  = (float*)(ws + 4096);      // 4 KB
    uint8_t* ef8    = (uint8_t*)(ws + 8192);    // 256 KB

    hipLaunchKernelGGL(k_codeprep, dim3(64),    dim3(256), 0, stream,
                       cb, ef8, enorm, ticket);
    hipLaunchKernelGGL(k_main,     dim3(NBLK2), dim3(256), 0, stream,
                       x, out, ef8, enorm, psum, ticket, out + OUT_ELEMS);
}